// Round 3
// 270.063 us; speedup vs baseline: 2.4280x; 2.4280x over previous
//
#include <hip/hip_runtime.h>
#include <stdint.h>

#define K_DIM 1024
#define N_DIM 1024
#define BM 128
#define BN 128
#define BK 64
#define NKT (K_DIM / BK)          // 16 K-tiles
#define TILE_BYTES (BM * BK)      // 8192 B per (row-block, k-tile)
#define W_BLOCKS 256              // weight-pack blocks in prep kernel
#define XQ_BLOCKS 2048            // x-quant grid-stride blocks in prep kernel
#define LDA 80                    // fused-fallback LDS stride

typedef int v4i __attribute__((ext_vector_type(4)));

__device__ __forceinline__ int quant1(float f, float inv) {
    return (int)fminf(fmaxf(rintf(f * inv), -128.f), 127.f);
}
__device__ __forceinline__ uint32_t pack4(int a, int b, int c, int d) {
    return (uint32_t)(a & 255) | ((uint32_t)(b & 255) << 8) |
           ((uint32_t)(c & 255) << 16) | ((uint32_t)(d & 255) << 24);
}
// Swizzled byte offset inside an 8 KB tile: row r in [0,128), col c in [0,64).
// XOR bits 4-6 with (r&7): bijective (bit6 becomes r0^r2; r2 lives untouched
// in bit 8, so invertible), 16B-alignment preserved. Fragment reads (16 lanes
// at stride 64 B, fixed col) spread across all 8 four-bank groups.
__device__ __forceinline__ int swz(int r, int c) {
    return (r * BK + c) ^ ((r & 7) << 4);
}
__device__ __forceinline__ bool probe_x_is_f32(const void* xptr) {
    // even halfwords: bf16/f16-origin data decodes mostly into [2^-3, 2);
    // f32-widened x has lo halfwords = mantissa<<13, ~none in range.
    const uint16_t* xu = (const uint16_t*)xptr;
    int lane = (int)(threadIdx.x & 63);
    float pv = __uint_as_float(((uint32_t)xu[2 * lane]) << 16);
    float pa = fabsf(pv);
    unsigned long long mx = __ballot(pa >= 0.125f && pa < 2.0f);
    return (__popcll(mx) < 32);
}

// ================= split path: prep (quantize + pack, swizzled tiles) =======
__global__ __launch_bounds__(256) void prep_kernel(
    const void* __restrict__ xptr,
    const int*  __restrict__ w32,
    const float* __restrict__ ascale_p,
    uint8_t* __restrict__ xq,
    uint8_t* __restrict__ wq,
    int M)
{
    const float inv = 1.0f / ascale_p[0];
    const int tid = threadIdx.x;

    if (blockIdx.x < W_BLOCKS) {
        // weight pack: 256 blocks x 256 threads x 16 elems = 1M elems, once
        int c = blockIdx.x * 256 + tid;           // [0, 65536)
        int q = c & 3;                            // 16-col chunk within k-tile
        int r = (c >> 2) & 127;                   // row within tile
        int t = c >> 9;                           // nblk*NKT + kb, [0,128)
        size_t row = (size_t)(t >> 4) * BM + r;
        int    col = (t & 15) * BK + q * 16;
        const int4* src = (const int4*)(w32 + row * K_DIM + col);
        uint32_t pk[4];
#pragma unroll
        for (int g = 0; g < 4; g++) {
            int4 v = src[g];
            pk[g] = pack4(v.x, v.y, v.z, v.w);
        }
        *(uint4*)(wq + ((size_t)t << 13) + swz(r, q * 16)) =
            make_uint4(pk[0], pk[1], pk[2], pk[3]);
        return;
    }

    const bool x_is_f32 = probe_x_is_f32(xptr);
    const int XC = M * (K_DIM / 16);              // total 16-elem chunks
    const int stride = XQ_BLOCKS * 256;
    for (int c = (blockIdx.x - W_BLOCKS) * 256 + tid; c < XC; c += stride) {
        int q = c & 3;
        int r = (c >> 2) & 127;
        int t = c >> 9;                           // mblk*NKT + kb
        size_t row = (size_t)(t >> 4) * BM + r;
        int    col = (t & 15) * BK + q * 16;
        uint32_t pk[4];
        if (x_is_f32) {
            const float4* src = (const float4*)((const float*)xptr + row * K_DIM + col);
#pragma unroll
            for (int g = 0; g < 4; g++) {
                float4 v = src[g];
                pk[g] = pack4(quant1(v.x, inv), quant1(v.y, inv),
                              quant1(v.z, inv), quant1(v.w, inv));
            }
        } else {
            const uint4* src = (const uint4*)((const uint16_t*)xptr + row * K_DIM + col);
            union { uint4 v[2]; uint32_t u[8]; } ax;
            ax.v[0] = src[0]; ax.v[1] = src[1];
#pragma unroll
            for (int i = 0; i < 4; i++) {
                uint32_t wa = ax.u[2 * i], wb = ax.u[2 * i + 1];
                pk[i] = pack4(quant1(__uint_as_float(wa << 16), inv),
                              quant1(__uint_as_float(wa & 0xffff0000u), inv),
                              quant1(__uint_as_float(wb << 16), inv),
                              quant1(__uint_as_float(wb & 0xffff0000u), inv));
            }
        }
        *(uint4*)(xq + ((size_t)t << 13) + swz(r, q * 16)) =
            make_uint4(pk[0], pk[1], pk[2], pk[3]);
    }
}

// ================= split path: GEMM (staging = global_load_lds memcpy) ======
#define GLOAD16(gsrc, ldst) \
    __builtin_amdgcn_global_load_lds( \
        (const __attribute__((address_space(1))) uint32_t*)(const void*)(gsrc), \
        (__attribute__((address_space(3))) uint32_t*)(void*)(ldst), 16, 0, 0)

__global__ __launch_bounds__(256, 4) void int8_gemm_kernel(
    const uint8_t* __restrict__ xq,
    const uint8_t* __restrict__ wq,
    const float* __restrict__ wscale,
    const float* __restrict__ ascale_p,
    const float* __restrict__ bias,
    float* __restrict__ out)
{
    __shared__ uint8_t lA[2][TILE_BYTES];   // 16 KB
    __shared__ uint8_t lB[2][TILE_BYTES];   // 16 KB -> 4 blocks/CU

    const int tid  = threadIdx.x;
    const int lane = tid & 63;
    const int wave = tid >> 6;
    const int wm   = wave >> 1;
    const int wn   = wave & 1;
    const int quad = lane >> 4;
    const int l16  = lane & 15;

    // bijective XCD swizzle (grid = numm*8, divisible by 8): each XCD gets a
    // contiguous mblk range; all 8 n-blocks of one x panel share an L2.
    const int numm = (int)gridDim.x >> 3;
    const int logical = ((int)blockIdx.x & 7) * numm + ((int)blockIdx.x >> 3);
    const int mblk = logical >> 3;
    const int nblk = logical & 7;

    const uint8_t* srcA = xq + (size_t)mblk * (NKT * TILE_BYTES) + tid * 16;
    const uint8_t* srcB = wq + (size_t)nblk * (NKT * TILE_BYTES) + tid * 16;

    int offA[4], offB[4];
#pragma unroll
    for (int i = 0; i < 4; i++) {
        offA[i] = swz(wm * 64 + i * 16 + l16, quad * 16);
        offB[i] = swz(wn * 64 + i * 16 + l16, quad * 16);
    }

    v4i acc[4][4] = {};

    // prologue: stage k-tile 0 into buffer 0 (8 KB A + 8 KB B, contiguous;
    // per wave the LDS dest is base + lane*16 -> matches gload_lds semantics)
    GLOAD16(srcA,        &lA[0][tid * 16]);
    GLOAD16(srcA + 4096, &lA[0][4096 + tid * 16]);
    GLOAD16(srcB,        &lB[0][tid * 16]);
    GLOAD16(srcB + 4096, &lB[0][4096 + tid * 16]);

    int cur = 0;
    for (int kb = 0; kb < NKT; kb++) {
        __syncthreads();                       // drains vmcnt: buf[cur] ready
        if (kb + 1 < NKT) {                    // issue next tile BEFORE compute
            const uint8_t* sa = srcA + (size_t)(kb + 1) * TILE_BYTES;
            const uint8_t* sb = srcB + (size_t)(kb + 1) * TILE_BYTES;
            GLOAD16(sa,        &lA[cur ^ 1][tid * 16]);          // loads stay
            GLOAD16(sa + 4096, &lA[cur ^ 1][4096 + tid * 16]);   // in flight
            GLOAD16(sb,        &lB[cur ^ 1][tid * 16]);          // across the
            GLOAD16(sb + 4096, &lB[cur ^ 1][4096 + tid * 16]);   // compute
        }
        v4i af[4], bf[4];
#pragma unroll
        for (int i = 0; i < 4; i++) {
            af[i] = *(const v4i*)&lA[cur][offA[i]];
            bf[i] = *(const v4i*)&lB[cur][offB[i]];
        }
#pragma unroll
        for (int mt = 0; mt < 4; mt++)
#pragma unroll
            for (int nt = 0; nt < 4; nt++)
                acc[mt][nt] = __builtin_amdgcn_mfma_i32_16x16x64_i8(
                    af[mt], bf[nt], acc[mt][nt], 0, 0, 0);
        cur ^= 1;
    }

    // epilogue: dequant + bias (C/D: col = l16, row = quad*4 + r)
    const float s = ascale_p[0];
    const int m0 = mblk * BM, n0 = nblk * BN;
    float osc[4], obi[4];
#pragma unroll
    for (int nt = 0; nt < 4; nt++) {
        int col = n0 + wn * 64 + nt * 16 + l16;
        osc[nt] = s * wscale[col];
        obi[nt] = bias[col];
    }
#pragma unroll
    for (int mt = 0; mt < 4; mt++) {
        int rowb = m0 + wm * 64 + mt * 16 + quad * 4;
#pragma unroll
        for (int nt = 0; nt < 4; nt++) {
            int col = n0 + wn * 64 + nt * 16 + l16;
#pragma unroll
            for (int r = 0; r < 4; r++) {
                out[(size_t)(rowb + r) * N_DIM + col] =
                    (float)acc[mt][nt][r] * osc[nt] + obi[nt];
            }
        }
    }
}

// ================= fallback: proven fused kernel (R0, 655 us) ===============
template<bool X_F32>
__device__ __forceinline__ void gemm_body(
    int8_t* lA, int8_t* lB,
    const void* __restrict__ xptr,
    const int* __restrict__ w32,
    const float* __restrict__ wscale,
    const float s,
    const float* __restrict__ bias,
    float* __restrict__ out)
{
    const int tid  = threadIdx.x;
    const int lane = tid & 63;
    const int wave = tid >> 6;
    const int wm   = wave >> 1;
    const int wn   = wave & 1;
    const int quad = lane >> 4;
    const int l16  = lane & 15;

    const int mblk = (int)blockIdx.x >> 3;
    const int nblk = (int)blockIdx.x & 7;
    const int m0 = mblk * BM;
    const int n0 = nblk * BN;

    const float inv = 1.0f / s;
    const int ar = tid >> 1;
    const int ah = (tid & 1) * 32;

    const float*    xrowf = (const float*)xptr    + (size_t)(m0 + ar) * K_DIM + ah;
    const uint16_t* xrowh = (const uint16_t*)xptr + (size_t)(m0 + ar) * K_DIM + ah;
    const int*      wrow  = w32 + (size_t)(n0 + ar) * K_DIM + ah;

    v4i acc[4][4] = {};

    for (int kb = 0; kb < K_DIM; kb += BK) {
        {
            uint32_t pk[8];
            if (X_F32) {
                const float4* xs = (const float4*)(xrowf + kb);
#pragma unroll
                for (int g = 0; g < 8; g++) {
                    float4 v = xs[g];
                    pk[g] = pack4(quant1(v.x, inv), quant1(v.y, inv),
                                  quant1(v.z, inv), quant1(v.w, inv));
                }
            } else {
                const uint4* xs = (const uint4*)(xrowh + kb);
                union { uint4 v[4]; uint32_t u[16]; } ax;
                ax.v[0] = xs[0]; ax.v[1] = xs[1]; ax.v[2] = xs[2]; ax.v[3] = xs[3];
#pragma unroll
                for (int i = 0; i < 8; i++) {
                    uint32_t wa = ax.u[2 * i], wb = ax.u[2 * i + 1];
                    pk[i] = pack4(quant1(__uint_as_float(wa << 16), inv),
                                  quant1(__uint_as_float(wa & 0xffff0000u), inv),
                                  quant1(__uint_as_float(wb << 16), inv),
                                  quant1(__uint_as_float(wb & 0xffff0000u), inv));
                }
            }
            uint4* adst = (uint4*)&lA[ar * LDA + ah];
            adst[0] = make_uint4(pk[0], pk[1], pk[2], pk[3]);
            adst[1] = make_uint4(pk[4], pk[5], pk[6], pk[7]);
        }
        {
            const int4* ws4 = (const int4*)(wrow + kb);
            uint32_t pb[8];
#pragma unroll
            for (int g = 0; g < 8; g++) {
                int4 v = ws4[g];
                pb[g] = pack4(v.x, v.y, v.z, v.w);
            }
            uint4* bdst = (uint4*)&lB[ar * LDA + ah];
            bdst[0] = make_uint4(pb[0], pb[1], pb[2], pb[3]);
            bdst[1] = make_uint4(pb[4], pb[5], pb[6], pb[7]);
        }
        __syncthreads();

        v4i af[4], bf[4];
#pragma unroll
        for (int mt = 0; mt < 4; mt++)
            af[mt] = *(const v4i*)&lA[(wm * 64 + mt * 16 + l16) * LDA + quad * 16];
#pragma unroll
        for (int nt = 0; nt < 4; nt++)
            bf[nt] = *(const v4i*)&lB[(wn * 64 + nt * 16 + l16) * LDA + quad * 16];
#pragma unroll
        for (int mt = 0; mt < 4; mt++)
#pragma unroll
            for (int nt = 0; nt < 4; nt++)
                acc[mt][nt] = __builtin_amdgcn_mfma_i32_16x16x64_i8(af[mt], bf[nt], acc[mt][nt], 0, 0, 0);
        __syncthreads();
    }

    float osc[4], obi[4];
#pragma unroll
    for (int nt = 0; nt < 4; nt++) {
        int col = n0 + wn * 64 + nt * 16 + l16;
        osc[nt] = s * wscale[col];
        obi[nt] = bias[col];
    }
#pragma unroll
    for (int mt = 0; mt < 4; mt++) {
        int rowb = m0 + wm * 64 + mt * 16 + quad * 4;
#pragma unroll
        for (int nt = 0; nt < 4; nt++) {
            int col = n0 + wn * 64 + nt * 16 + l16;
#pragma unroll
            for (int r = 0; r < 4; r++) {
                out[(size_t)(rowb + r) * N_DIM + col] =
                    (float)acc[mt][nt][r] * osc[nt] + obi[nt];
            }
        }
    }
}

__global__ __launch_bounds__(256, 2) void int8_linear_fused(
    const void* __restrict__ xptr,
    const int* __restrict__ w32,
    const float* __restrict__ wscale,
    const float* __restrict__ ascale_p,
    const float* __restrict__ bias,
    float* __restrict__ out)
{
    __shared__ int8_t lA[BM * LDA];
    __shared__ int8_t lB[BN * LDA];
    const bool x_is_f32 = probe_x_is_f32(xptr);
    const float s = ascale_p[0];
    if (x_is_f32) gemm_body<true >(lA, lB, xptr, w32, wscale, s, bias, out);
    else          gemm_body<false>(lA, lB, xptr, w32, wscale, s, bias, out);
}

// ================= launch ===================================================
extern "C" void kernel_launch(void* const* d_in, const int* in_sizes, int n_in,
                              void* d_out, int out_size, void* d_ws, size_t ws_size,
                              hipStream_t stream) {
    const void*  xptr   = d_in[0];              // f16 widened to f32 by harness
    const int*   w32    = (const int*)d_in[1];  // int8 widened to int32
    const float* wscale = (const float*)d_in[2];
    const float* ascale = (const float*)d_in[3];
    const float* bias   = (const float*)d_in[4];
    float*       out    = (float*)d_out;        // f16 output -> float*

    int M = in_sizes[0] / K_DIM;                // 32768
    size_t need = (size_t)M * K_DIM + (size_t)N_DIM * K_DIM;  // 34.6 MB

    // split path requires: workspace, M a multiple of BM, and the exact
    // M (=32768) the prep grid constants were sized for; else proven fallback.
    bool split_ok = (d_ws != nullptr) && (ws_size >= need) &&
                    (M == 32768) && (M % BM == 0);

    if (split_ok) {
        uint8_t* xq = (uint8_t*)d_ws;
        uint8_t* wq = xq + (size_t)M * K_DIM;
        prep_kernel<<<dim3(W_BLOCKS + XQ_BLOCKS), 256, 0, stream>>>(
            xptr, w32, ascale, xq, wq, M);
        int numm = M / BM;
        int8_gemm_kernel<<<dim3(numm * 8), 256, 0, stream>>>(
            xq, wq, wscale, ascale, bias, out);
    } else {
        dim3 grid((M / BM) * (N_DIM / BN));     // 2048 blocks
        int8_linear_fused<<<grid, 256, 0, stream>>>(
            xptr, w32, wscale, ascale, bias, out);
    }
}